// Round 6
// baseline (211.842 us; speedup 1.0000x reference)
//
#include <hip/hip_runtime.h>

// ============================================================================
// WignerKernelReducedCost: per-b CG tensor-product tower.
//   out[b,0] = x0[b]
//   Y = combine(X, X, 3)           (7 keys: 0_1, 1_±1, 2_±1, 3_±1)
//   out[b,1] = Y['0_1']
//   out[b,2] = combine(Y, X, 0)['0_1'] = sum_l inv(2l+1) signed dot(Y[l_1], X_l)
//   out[b,3] = combine(Y, Y, 0)['0_1'] = sum_{l,s} inv(2l+1) selfdot(Y[l_s])
//
// Round-6 = round-5 (opaque value fences between keys: SPILLS FIXED, WRITE
// 864->14.7MB, dur 610->52us rocprof, VALUBusy 63%) plus:
//   (a) amdgpu_waves_per_eu(4,4): R5 pinned 2 waves/EU but the allocator only
//       used 128 VGPR -> HW allows 4 waves/EU at the SAME budget. Doubles
//       latency hiding for the residual ~57B/thread spill + fma chains.
//   (b) dual parity-interleaved accumulator chains in triElem/dot00 (fmaf is
//       4-cyc latency / 2-cyc issue; one serial chain caps a wave at 50%).
// History: R1 (256 VGPR) 570MB scratch / R2 (64) 2.2GB / R3 (sched_barrier,
// 128) 1.45GB -- IR-level GVN/CSE hoisted cross-key temporaries; only the
// asm volatile("" : "+v") value fences (R5) stopped it.
// All CG coefficients fold to immediates at compile time.
// ============================================================================

#define SCHED_FENCE() __builtin_amdgcn_sched_barrier(0)

template <int N>
__device__ __forceinline__ void opaque(float (&A)[N]) {
#pragma unroll
  for (int i = 0; i < N; ++i) asm volatile("" : "+v"(A[i]));
}
__device__ __forceinline__ void opaque1(float& x) { asm volatile("" : "+v"(x)); }

// ---------- compile-time Clebsch-Gordan (Racah formula) ----------
constexpr double cfact(int n) { double r = 1.0; for (int i = 2; i <= n; ++i) r *= (double)i; return r; }

constexpr double csqrt(double x) {
  if (x <= 0.0) return 0.0;
  double g = x > 1.0 ? x : 1.0;
  for (int i = 0; i < 100; ++i) g = 0.5 * (g + x / g);
  return g;
}

constexpr double cg_val(int l1, int l2, int L, int m1, int m2) {
  const int M = m1 + m2;
  if (M < -L || M > L) return 0.0;
  const double pref0 = csqrt((2.0 * L + 1.0) * cfact(L + l1 - l2) * cfact(L - l1 + l2) *
                             cfact(l1 + l2 - L) / cfact(l1 + l2 + L + 1));
  const double pref = pref0 * csqrt(cfact(L + M) * cfact(L - M) * cfact(l1 - m1) *
                                    cfact(l1 + m1) * cfact(l2 - m2) * cfact(l2 + m2));
  double s = 0.0;
  for (int k = 0; k <= l1 + l2 - L; ++k) {
    if (l1 - m1 - k < 0 || l2 + m2 - k < 0 || L - l2 + m1 + k < 0 || L - l1 - m2 + k < 0) continue;
    const double t = 1.0 / (cfact(k) * cfact(l1 + l2 - L - k) * cfact(l1 - m1 - k) *
                            cfact(l2 + m2 - k) * cfact(L - l2 + m1 + k) * cfact(L - l1 - m2 + k));
    s += (k & 1) ? -t : t;
  }
  return pref * s;
}

// Table a[mi][kk] = <l1 (mi-l1); l2 (kk-L-(mi-l1)) | L (kk-L)>  (0 if m2 out of range)
template <int l1, int l2, int L>
struct CG2T {
  double a[2 * l1 + 1][2 * L + 1];
  constexpr CG2T() : a{} {
    for (int mi = 0; mi < 2 * l1 + 1; ++mi)
      for (int kk = 0; kk < 2 * L + 1; ++kk) {
        const int m1 = mi - l1, M = kk - L, m2 = M - m1;
        a[mi][kk] = (m2 < -l2 || m2 > l2) ? 0.0 : cg_val(l1, l2, L, m1, m2);
      }
  }
};
template <int l1, int l2, int L>
constexpr CG2T<l1, l2, L> CG2v = CG2T<l1, l2, L>();

// ---------- one (l1,l2,L) triple: Y[k,j] += W * C[m,n,k] C[p,q,j] K1[m,p] K2[n,q] ----------
// W=2 encodes the (l1,l2)/(l2,l1) pair symmetry (contributions identical).
// For l1==l2 (K1==K2), terms (m,p) and (n,q)=(k-m, j-p) have identical
// coefficient and product -> keep id1<=id2 with factor 2.
// Two parity-interleaved accumulator chains (compile-time after unroll).
template <int l1, int l2, int L, int W>
__device__ __forceinline__ void tri(const float (&K1)[(2 * l1 + 1) * (2 * l1 + 1)],
                                    const float (&K2)[(2 * l2 + 1) * (2 * l2 + 1)],
                                    float (&Y)[(2 * L + 1) * (2 * L + 1)]) {
  constexpr int d1 = 2 * l1 + 1, d2 = 2 * l2 + 1, dL = 2 * L + 1;
#pragma unroll
  for (int kk = 0; kk < dL; ++kk) {
#pragma unroll
    for (int jj = 0; jj < dL; ++jj) {
      float a0 = 0.f, a1 = 0.f;
#pragma unroll
      for (int mi = 0; mi < d1; ++mi) {
        const int ni = (kk - L) - (mi - l1) + l2;  // m2 index in K2
        if (ni < 0 || ni >= d2) continue;
#pragma unroll
        for (int pi = 0; pi < d1; ++pi) {
          const int qi = (jj - L) - (pi - l1) + l2;
          if (qi < 0 || qi >= d2) continue;
          const double c0 = CG2v<l1, l2, L>.a[mi][kk] * CG2v<l1, l2, L>.a[pi][jj];
          if (c0 == 0.0) continue;  // folded at compile time
          double c = c0 * (double)W;
          if constexpr (l1 == l2) {
            const int id1 = mi * d1 + pi, id2 = ni * d1 + qi;
            if (id1 > id2) continue;   // partner term covers it
            if (id1 < id2) c *= 2.0;   // merged pair
          }
          if ((mi + pi) & 1)
            a1 = fmaf((float)c * K1[mi * d1 + pi], K2[ni * d2 + qi], a1);
          else
            a0 = fmaf((float)c * K1[mi * d1 + pi], K2[ni * d2 + qi], a0);
        }
      }
      Y[kk * dL + jj] += a0 + a1;
    }
  }
}

// ---------- L=0 invariant dot:  sum_{i,j} (-1)^(i+j)/(2l+1) A[i,j] B[2l-i,2l-j] ----------
template <int l, bool SELF>
__device__ __forceinline__ float dot00(const float (&A)[(2 * l + 1) * (2 * l + 1)],
                                       const float (&Bm)[(2 * l + 1) * (2 * l + 1)]) {
  constexpr int d = 2 * l + 1;
  float a0 = 0.f, a1 = 0.f;
#pragma unroll
  for (int i = 0; i < d; ++i) {
#pragma unroll
    for (int j = 0; j < d; ++j) {
      const int i2 = 2 * l - i, j2 = 2 * l - j;
      double c = (((i + j) & 1) ? -1.0 : 1.0) / (double)d;
      if constexpr (SELF) {  // A==Bm: (i,j) <-> (i2,j2) give identical products
        const int id1 = i * d + j, id2 = i2 * d + j2;
        if (id1 > id2) continue;
        if (id1 < id2) c *= 2.0;
      }
      if (j & 1)
        a1 = fmaf((float)c * A[i * d + j], Bm[i2 * d + j2], a1);
      else
        a0 = fmaf((float)c * A[i * d + j], Bm[i2 * d + j2], a0);
    }
  }
  return a0 + a1;
}

__global__ __launch_bounds__(256)
__attribute__((amdgpu_waves_per_eu(4, 4)))
void wigner_kernel(
    const float* __restrict__ x0, const float* __restrict__ x1,
    const float* __restrict__ x2, const float* __restrict__ x3,
    float* __restrict__ out, int n) {
  const int b = blockIdx.x * blockDim.x + threadIdx.x;
  if (b >= n) return;

  float X0[1], X1[9], X2[25], X3[49];
  X0[0] = x0[b];
#pragma unroll
  for (int i = 0; i < 9; ++i) X1[i] = x1[b * 9 + i];
#pragma unroll
  for (int i = 0; i < 25; ++i) X2[i] = x2[b * 25 + i];
#pragma unroll
  for (int i = 0; i < 49; ++i) X3[i] = x3[b * 49 + i];

  float o2, o3 = 0.f, o4 = 0.f;

  // full value fence: X becomes "new" values; nothing computed from old X
  // can be reused past this point; also pins schedule.
#define KEY_FENCE()                                                   \
  do {                                                                \
    opaque(X0); opaque(X1); opaque(X2); opaque(X3);                   \
    opaque1(o3); opaque1(o4);                                         \
    SCHED_FENCE();                                                    \
  } while (0)

  KEY_FENCE();

  {  // key 0_1 : (0,0) (1,1) (2,2) (3,3)
    float Y[1] = {};
    tri<0, 0, 0, 1>(X0, X0, Y);
    tri<1, 1, 0, 1>(X1, X1, Y);
    tri<2, 2, 0, 1>(X2, X2, Y);
    tri<3, 3, 0, 1>(X3, X3, Y);
    o2 = Y[0];
    o3 = fmaf(Y[0], X0[0], o3);
    o4 = fmaf(Y[0], Y[0], o4);
  }
  KEY_FENCE();
  {  // key 1_1 : (0,1)x2 (1,2)x2 (2,3)x2
    float Y[9] = {};
    tri<0, 1, 1, 2>(X0, X1, Y);
    tri<1, 2, 1, 2>(X1, X2, Y);
    tri<2, 3, 1, 2>(X2, X3, Y);
    o3 += dot00<1, false>(Y, X1);
    o4 += dot00<1, true>(Y, Y);
  }
  KEY_FENCE();
  {  // key 1_-1 : (1,1) (2,2) (3,3)
    float Y[9] = {};
    tri<1, 1, 1, 1>(X1, X1, Y);
    tri<2, 2, 1, 1>(X2, X2, Y);
    tri<3, 3, 1, 1>(X3, X3, Y);
    o4 += dot00<1, true>(Y, Y);
  }
  KEY_FENCE();
  {  // key 2_1 : (0,2)x2 (1,1) (1,3)x2 (2,2) (3,3)
    float Y[25] = {};
    tri<0, 2, 2, 2>(X0, X2, Y);
    tri<1, 1, 2, 1>(X1, X1, Y);
    tri<1, 3, 2, 2>(X1, X3, Y);
    tri<2, 2, 2, 1>(X2, X2, Y);
    tri<3, 3, 2, 1>(X3, X3, Y);
    o3 += dot00<2, false>(Y, X2);
    o4 += dot00<2, true>(Y, Y);
  }
  KEY_FENCE();
  {  // key 2_-1 : (1,2)x2 (2,3)x2
    float Y[25] = {};
    tri<1, 2, 2, 2>(X1, X2, Y);
    tri<2, 3, 2, 2>(X2, X3, Y);
    o4 += dot00<2, true>(Y, Y);
  }
  KEY_FENCE();
  {  // key 3_1 : (0,3)x2 (1,2)x2 (2,3)x2
    float Y[49] = {};
    tri<0, 3, 3, 2>(X0, X3, Y);
    tri<1, 2, 3, 2>(X1, X2, Y);
    tri<2, 3, 3, 2>(X2, X3, Y);
    o3 += dot00<3, false>(Y, X3);
    o4 += dot00<3, true>(Y, Y);
  }
  KEY_FENCE();
  {  // key 3_-1 : (1,3)x2 (2,2) (3,3)
    float Y[49] = {};
    tri<1, 3, 3, 2>(X1, X3, Y);
    tri<2, 2, 3, 1>(X2, X2, Y);
    tri<3, 3, 3, 1>(X3, X3, Y);
    o4 += dot00<3, true>(Y, Y);
  }
#undef KEY_FENCE

  reinterpret_cast<float4*>(out)[b] = make_float4(X0[0], o2, o3, o4);
}

extern "C" void kernel_launch(void* const* d_in, const int* in_sizes, int n_in,
                              void* d_out, int out_size, void* d_ws, size_t ws_size,
                              hipStream_t stream) {
  const float* x0 = (const float*)d_in[0];
  const float* x1 = (const float*)d_in[1];
  const float* x2 = (const float*)d_in[2];
  const float* x3 = (const float*)d_in[3];
  float* out = (float*)d_out;
  const int n = in_sizes[0];  // B (x0 has 1 element per b)
  const int block = 256;
  const int grid = (n + block - 1) / block;
  wigner_kernel<<<grid, block, 0, stream>>>(x0, x1, x2, x3, out, n);
}

// Round 8
// 151.761 us; speedup vs baseline: 1.3959x; 1.3959x over previous
//
#include <hip/hip_runtime.h>

// ============================================================================
// WignerKernelReducedCost: per-b CG tensor-product tower.
//   out[b,0] = x0[b]
//   Y = combine(X, X, 3)           (7 keys: 0_1, 1_±1, 2_±1, 3_±1)
//   out[b,1] = Y['0_1']
//   out[b,2] = combine(Y, X, 0)['0_1'] = sum_l inv(2l+1) signed dot(Y[l_1], X_l)
//   out[b,3] = combine(Y, Y, 0)['0_1'] = sum_{l,s} inv(2l+1) selfdot(Y[l_s])
//
// Round-8 == round-7 (GPU acquisition timed out; never ran):
// R5 (opaque value fences; best: 52us rocprof, VALUBusy 63%, 128 VGPR,
// ~57B/thread spill) + R6's dual accumulator chains + waves_per_eu (3,3).
// Rationale: per-key live set ~150 floats fits the 3-wave budget (170 VGPR)
// spill-free; (2,2) left 2x latency-hiding unused, (4,4) made the allocator
// pick the 64-VGPR/8-wave budget and spill 1.2KB/thread (R6 regression:
// 133us). Occupancy attr sets a MINIMUM waves target -> allocator
// under-allocates regs; 3 waves is the largest target whose budget covers
// the live set.
// History: R1 (256 VGPR) 570MB scratch / R2 (64) 2.2GB / R3 (sched_barrier,
// 128) 1.45GB -- IR-level GVN/CSE hoisted cross-key temporaries; only the
// asm volatile("" : "+v") value fences (R5) stopped it.
// All CG coefficients fold to immediates at compile time.
// ============================================================================

#define SCHED_FENCE() __builtin_amdgcn_sched_barrier(0)

template <int N>
__device__ __forceinline__ void opaque(float (&A)[N]) {
#pragma unroll
  for (int i = 0; i < N; ++i) asm volatile("" : "+v"(A[i]));
}
__device__ __forceinline__ void opaque1(float& x) { asm volatile("" : "+v"(x)); }

// ---------- compile-time Clebsch-Gordan (Racah formula) ----------
constexpr double cfact(int n) { double r = 1.0; for (int i = 2; i <= n; ++i) r *= (double)i; return r; }

constexpr double csqrt(double x) {
  if (x <= 0.0) return 0.0;
  double g = x > 1.0 ? x : 1.0;
  for (int i = 0; i < 100; ++i) g = 0.5 * (g + x / g);
  return g;
}

constexpr double cg_val(int l1, int l2, int L, int m1, int m2) {
  const int M = m1 + m2;
  if (M < -L || M > L) return 0.0;
  const double pref0 = csqrt((2.0 * L + 1.0) * cfact(L + l1 - l2) * cfact(L - l1 + l2) *
                             cfact(l1 + l2 - L) / cfact(l1 + l2 + L + 1));
  const double pref = pref0 * csqrt(cfact(L + M) * cfact(L - M) * cfact(l1 - m1) *
                                    cfact(l1 + m1) * cfact(l2 - m2) * cfact(l2 + m2));
  double s = 0.0;
  for (int k = 0; k <= l1 + l2 - L; ++k) {
    if (l1 - m1 - k < 0 || l2 + m2 - k < 0 || L - l2 + m1 + k < 0 || L - l1 - m2 + k < 0) continue;
    const double t = 1.0 / (cfact(k) * cfact(l1 + l2 - L - k) * cfact(l1 - m1 - k) *
                            cfact(l2 + m2 - k) * cfact(L - l2 + m1 + k) * cfact(L - l1 - m2 + k));
    s += (k & 1) ? -t : t;
  }
  return pref * s;
}

// Table a[mi][kk] = <l1 (mi-l1); l2 (kk-L-(mi-l1)) | L (kk-L)>  (0 if m2 out of range)
template <int l1, int l2, int L>
struct CG2T {
  double a[2 * l1 + 1][2 * L + 1];
  constexpr CG2T() : a{} {
    for (int mi = 0; mi < 2 * l1 + 1; ++mi)
      for (int kk = 0; kk < 2 * L + 1; ++kk) {
        const int m1 = mi - l1, M = kk - L, m2 = M - m1;
        a[mi][kk] = (m2 < -l2 || m2 > l2) ? 0.0 : cg_val(l1, l2, L, m1, m2);
      }
  }
};
template <int l1, int l2, int L>
constexpr CG2T<l1, l2, L> CG2v = CG2T<l1, l2, L>();

// ---------- one (l1,l2,L) triple: Y[k,j] += W * C[m,n,k] C[p,q,j] K1[m,p] K2[n,q] ----------
// W=2 encodes the (l1,l2)/(l2,l1) pair symmetry (contributions identical).
// For l1==l2 (K1==K2), terms (m,p) and (n,q)=(k-m, j-p) have identical
// coefficient and product -> keep id1<=id2 with factor 2.
// Two parity-interleaved accumulator chains (compile-time after unroll).
template <int l1, int l2, int L, int W>
__device__ __forceinline__ void tri(const float (&K1)[(2 * l1 + 1) * (2 * l1 + 1)],
                                    const float (&K2)[(2 * l2 + 1) * (2 * l2 + 1)],
                                    float (&Y)[(2 * L + 1) * (2 * L + 1)]) {
  constexpr int d1 = 2 * l1 + 1, d2 = 2 * l2 + 1, dL = 2 * L + 1;
#pragma unroll
  for (int kk = 0; kk < dL; ++kk) {
#pragma unroll
    for (int jj = 0; jj < dL; ++jj) {
      float a0 = 0.f, a1 = 0.f;
#pragma unroll
      for (int mi = 0; mi < d1; ++mi) {
        const int ni = (kk - L) - (mi - l1) + l2;  // m2 index in K2
        if (ni < 0 || ni >= d2) continue;
#pragma unroll
        for (int pi = 0; pi < d1; ++pi) {
          const int qi = (jj - L) - (pi - l1) + l2;
          if (qi < 0 || qi >= d2) continue;
          const double c0 = CG2v<l1, l2, L>.a[mi][kk] * CG2v<l1, l2, L>.a[pi][jj];
          if (c0 == 0.0) continue;  // folded at compile time
          double c = c0 * (double)W;
          if constexpr (l1 == l2) {
            const int id1 = mi * d1 + pi, id2 = ni * d1 + qi;
            if (id1 > id2) continue;   // partner term covers it
            if (id1 < id2) c *= 2.0;   // merged pair
          }
          if ((mi + pi) & 1)
            a1 = fmaf((float)c * K1[mi * d1 + pi], K2[ni * d2 + qi], a1);
          else
            a0 = fmaf((float)c * K1[mi * d1 + pi], K2[ni * d2 + qi], a0);
        }
      }
      Y[kk * dL + jj] += a0 + a1;
    }
  }
}

// ---------- L=0 invariant dot:  sum_{i,j} (-1)^(i+j)/(2l+1) A[i,j] B[2l-i,2l-j] ----------
template <int l, bool SELF>
__device__ __forceinline__ float dot00(const float (&A)[(2 * l + 1) * (2 * l + 1)],
                                       const float (&Bm)[(2 * l + 1) * (2 * l + 1)]) {
  constexpr int d = 2 * l + 1;
  float a0 = 0.f, a1 = 0.f;
#pragma unroll
  for (int i = 0; i < d; ++i) {
#pragma unroll
    for (int j = 0; j < d; ++j) {
      const int i2 = 2 * l - i, j2 = 2 * l - j;
      double c = (((i + j) & 1) ? -1.0 : 1.0) / (double)d;
      if constexpr (SELF) {  // A==Bm: (i,j) <-> (i2,j2) give identical products
        const int id1 = i * d + j, id2 = i2 * d + j2;
        if (id1 > id2) continue;
        if (id1 < id2) c *= 2.0;
      }
      if (j & 1)
        a1 = fmaf((float)c * A[i * d + j], Bm[i2 * d + j2], a1);
      else
        a0 = fmaf((float)c * A[i * d + j], Bm[i2 * d + j2], a0);
    }
  }
  return a0 + a1;
}

__global__ __launch_bounds__(256)
__attribute__((amdgpu_waves_per_eu(3, 3)))
void wigner_kernel(
    const float* __restrict__ x0, const float* __restrict__ x1,
    const float* __restrict__ x2, const float* __restrict__ x3,
    float* __restrict__ out, int n) {
  const int b = blockIdx.x * blockDim.x + threadIdx.x;
  if (b >= n) return;

  float X0[1], X1[9], X2[25], X3[49];
  X0[0] = x0[b];
#pragma unroll
  for (int i = 0; i < 9; ++i) X1[i] = x1[b * 9 + i];
#pragma unroll
  for (int i = 0; i < 25; ++i) X2[i] = x2[b * 25 + i];
#pragma unroll
  for (int i = 0; i < 49; ++i) X3[i] = x3[b * 49 + i];

  float o2, o3 = 0.f, o4 = 0.f;

  // full value fence: X becomes "new" values; nothing computed from old X
  // can be reused past this point; also pins schedule.
#define KEY_FENCE()                                                   \
  do {                                                                \
    opaque(X0); opaque(X1); opaque(X2); opaque(X3);                   \
    opaque1(o3); opaque1(o4);                                         \
    SCHED_FENCE();                                                    \
  } while (0)

  KEY_FENCE();

  {  // key 0_1 : (0,0) (1,1) (2,2) (3,3)
    float Y[1] = {};
    tri<0, 0, 0, 1>(X0, X0, Y);
    tri<1, 1, 0, 1>(X1, X1, Y);
    tri<2, 2, 0, 1>(X2, X2, Y);
    tri<3, 3, 0, 1>(X3, X3, Y);
    o2 = Y[0];
    o3 = fmaf(Y[0], X0[0], o3);
    o4 = fmaf(Y[0], Y[0], o4);
  }
  KEY_FENCE();
  {  // key 1_1 : (0,1)x2 (1,2)x2 (2,3)x2
    float Y[9] = {};
    tri<0, 1, 1, 2>(X0, X1, Y);
    tri<1, 2, 1, 2>(X1, X2, Y);
    tri<2, 3, 1, 2>(X2, X3, Y);
    o3 += dot00<1, false>(Y, X1);
    o4 += dot00<1, true>(Y, Y);
  }
  KEY_FENCE();
  {  // key 1_-1 : (1,1) (2,2) (3,3)
    float Y[9] = {};
    tri<1, 1, 1, 1>(X1, X1, Y);
    tri<2, 2, 1, 1>(X2, X2, Y);
    tri<3, 3, 1, 1>(X3, X3, Y);
    o4 += dot00<1, true>(Y, Y);
  }
  KEY_FENCE();
  {  // key 2_1 : (0,2)x2 (1,1) (1,3)x2 (2,2) (3,3)
    float Y[25] = {};
    tri<0, 2, 2, 2>(X0, X2, Y);
    tri<1, 1, 2, 1>(X1, X1, Y);
    tri<1, 3, 2, 2>(X1, X3, Y);
    tri<2, 2, 2, 1>(X2, X2, Y);
    tri<3, 3, 2, 1>(X3, X3, Y);
    o3 += dot00<2, false>(Y, X2);
    o4 += dot00<2, true>(Y, Y);
  }
  KEY_FENCE();
  {  // key 2_-1 : (1,2)x2 (2,3)x2
    float Y[25] = {};
    tri<1, 2, 2, 2>(X1, X2, Y);
    tri<2, 3, 2, 2>(X2, X3, Y);
    o4 += dot00<2, true>(Y, Y);
  }
  KEY_FENCE();
  {  // key 3_1 : (0,3)x2 (1,2)x2 (2,3)x2
    float Y[49] = {};
    tri<0, 3, 3, 2>(X0, X3, Y);
    tri<1, 2, 3, 2>(X1, X2, Y);
    tri<2, 3, 3, 2>(X2, X3, Y);
    o3 += dot00<3, false>(Y, X3);
    o4 += dot00<3, true>(Y, Y);
  }
  KEY_FENCE();
  {  // key 3_-1 : (1,3)x2 (2,2) (3,3)
    float Y[49] = {};
    tri<1, 3, 3, 2>(X1, X3, Y);
    tri<2, 2, 3, 1>(X2, X2, Y);
    tri<3, 3, 3, 1>(X3, X3, Y);
    o4 += dot00<3, true>(Y, Y);
  }
#undef KEY_FENCE

  reinterpret_cast<float4*>(out)[b] = make_float4(X0[0], o2, o3, o4);
}

extern "C" void kernel_launch(void* const* d_in, const int* in_sizes, int n_in,
                              void* d_out, int out_size, void* d_ws, size_t ws_size,
                              hipStream_t stream) {
  const float* x0 = (const float*)d_in[0];
  const float* x1 = (const float*)d_in[1];
  const float* x2 = (const float*)d_in[2];
  const float* x3 = (const float*)d_in[3];
  float* out = (float*)d_out;
  const int n = in_sizes[0];  // B (x0 has 1 element per b)
  const int block = 256;
  const int grid = (n + block - 1) / block;
  wigner_kernel<<<grid, block, 0, stream>>>(x0, x1, x2, x3, out, n);
}

// Round 9
// 126.579 us; speedup vs baseline: 1.6736x; 1.1989x over previous
//
#include <hip/hip_runtime.h>

// ============================================================================
// WignerKernelReducedCost: per-b CG tensor-product tower.
//   out[b,0] = x0[b]
//   Y = combine(X, X, 3)           (7 keys: 0_1, 1_±1, 2_±1, 3_±1)
//   out[b,1] = Y['0_1']
//   out[b,2] = combine(Y, X, 0)['0_1'] = sum_l inv(2l+1) signed dot(Y[l_1], X_l)
//   out[b,3] = combine(Y, Y, 0)['0_1'] = sum_{l,s} inv(2l+1) selfdot(Y[l_s])
//
// Round-9 = R5 (opaque value fences, waves_per_eu(2,2): best measured, 52us,
// 128 VGPR, 57B/thread residual spill, VALUBusy 63%) + dual accumulator
// chains + PAIR-STREAMING of every key (no Y arrays): each inversion pair
// {(i,j),(2l-i,2l-j)} is computed on the fly (each element exactly ONCE -
// pairs partition the grid, no recompute) and folded straight into o3/o4.
// Peak live set drops 140 -> ~95 floats < 128-VGPR budget => zero spill.
// waves_per_eu lesson (R6: (4,4)->64 VGPR 1.2KB spill; R8: (3,3)->84 VGPR
// 230B spill): the attr makes the allocator UNDER-allocate; (2,2) is the
// only setting that yields the 128 tier. Opaque-fence lesson (R1-R3):
// IR-level GVN/CSE hoists cross-key temporaries past any scheduler fence;
// only asm volatile("" : "+v") value fences stop it.
// All CG coefficients fold to immediates at compile time.
// ============================================================================

#define SCHED_FENCE() __builtin_amdgcn_sched_barrier(0)

template <int N>
__device__ __forceinline__ void opaque(float (&A)[N]) {
#pragma unroll
  for (int i = 0; i < N; ++i) asm volatile("" : "+v"(A[i]));
}
__device__ __forceinline__ void opaque1(float& x) { asm volatile("" : "+v"(x)); }

// ---------- compile-time Clebsch-Gordan (Racah formula) ----------
constexpr double cfact(int n) { double r = 1.0; for (int i = 2; i <= n; ++i) r *= (double)i; return r; }

constexpr double csqrt(double x) {
  if (x <= 0.0) return 0.0;
  double g = x > 1.0 ? x : 1.0;
  for (int i = 0; i < 100; ++i) g = 0.5 * (g + x / g);
  return g;
}

constexpr double cg_val(int l1, int l2, int L, int m1, int m2) {
  const int M = m1 + m2;
  if (M < -L || M > L) return 0.0;
  const double pref0 = csqrt((2.0 * L + 1.0) * cfact(L + l1 - l2) * cfact(L - l1 + l2) *
                             cfact(l1 + l2 - L) / cfact(l1 + l2 + L + 1));
  const double pref = pref0 * csqrt(cfact(L + M) * cfact(L - M) * cfact(l1 - m1) *
                                    cfact(l1 + m1) * cfact(l2 - m2) * cfact(l2 + m2));
  double s = 0.0;
  for (int k = 0; k <= l1 + l2 - L; ++k) {
    if (l1 - m1 - k < 0 || l2 + m2 - k < 0 || L - l2 + m1 + k < 0 || L - l1 - m2 + k < 0) continue;
    const double t = 1.0 / (cfact(k) * cfact(l1 + l2 - L - k) * cfact(l1 - m1 - k) *
                            cfact(l2 + m2 - k) * cfact(L - l2 + m1 + k) * cfact(L - l1 - m2 + k));
    s += (k & 1) ? -t : t;
  }
  return pref * s;
}

// Table a[mi][kk] = <l1 (mi-l1); l2 (kk-L-(mi-l1)) | L (kk-L)>  (0 if m2 out of range)
template <int l1, int l2, int L>
struct CG2T {
  double a[2 * l1 + 1][2 * L + 1];
  constexpr CG2T() : a{} {
    for (int mi = 0; mi < 2 * l1 + 1; ++mi)
      for (int kk = 0; kk < 2 * L + 1; ++kk) {
        const int m1 = mi - l1, M = kk - L, m2 = M - m1;
        a[mi][kk] = (m2 < -l2 || m2 > l2) ? 0.0 : cg_val(l1, l2, L, m1, m2);
      }
  }
};
template <int l1, int l2, int L>
constexpr CG2T<l1, l2, L> CG2v = CG2T<l1, l2, L>();

// ---------- contribution of one (l1,l2,L) triple to ONE Y element ----------
// W=2 encodes the (l1,l2)/(l2,l1) pair symmetry (contributions identical).
// For l1==l2 (K1==K2), terms (m,p) and (n,q) within the SAME element have
// identical coefficient and product -> keep id1<=id2 with factor 2.
// Dual parity-interleaved accumulator chains (compile-time after unroll).
template <int l1, int l2, int L, int W>
__device__ __forceinline__ float triElem(const float (&K1)[(2 * l1 + 1) * (2 * l1 + 1)],
                                         const float (&K2)[(2 * l2 + 1) * (2 * l2 + 1)],
                                         int kk, int jj) {
  constexpr int d1 = 2 * l1 + 1, d2 = 2 * l2 + 1;
  float a0 = 0.f, a1 = 0.f;
#pragma unroll
  for (int mi = 0; mi < d1; ++mi) {
    const int ni = (kk - L) - (mi - l1) + l2;  // m2 index in K2
    if (ni < 0 || ni >= d2) continue;
#pragma unroll
    for (int pi = 0; pi < d1; ++pi) {
      const int qi = (jj - L) - (pi - l1) + l2;
      if (qi < 0 || qi >= d2) continue;
      const double c0 = CG2v<l1, l2, L>.a[mi][kk] * CG2v<l1, l2, L>.a[pi][jj];
      if (c0 == 0.0) continue;  // folded at compile time
      double c = c0 * (double)W;
      if constexpr (l1 == l2) {
        const int id1 = mi * d1 + pi, id2 = ni * d1 + qi;
        if (id1 > id2) continue;   // partner term covers it
        if (id1 < id2) c *= 2.0;   // merged pair
      }
      if ((mi + pi) & 1)
        a1 = fmaf((float)c * K1[mi * d1 + pi], K2[ni * d2 + qi], a1);
      else
        a0 = fmaf((float)c * K1[mi * d1 + pi], K2[ni * d2 + qi], a0);
    }
  }
  return a0 + a1;
}

// ---------- stream one key: pairs {(i,j),(2l-i,2l-j)} -> o3/o4, no Y array ----------
// Each Y element is computed exactly once (pairs partition the d*d grid).
// o4 += inv(2l+1) * sum (-1)^(i+j) Y[i,j] Y[2l-i,2l-j]
// o3 += inv(2l+1) * sum (-1)^(i+j) Y[i,j] X[2l-i,2l-j]   (sig=+1 keys only)
template <int l, bool HAS_O3, typename F>
__device__ __forceinline__ void reduceKey(F yel, const float (&Xl)[(2 * l + 1) * (2 * l + 1)],
                                          float& o3, float& o4) {
  constexpr int d = 2 * l + 1;
  constexpr float inv = 1.0f / (float)d;
#pragma unroll
  for (int i = 0; i < d; ++i) {
#pragma unroll
    for (int j = 0; j < d; ++j) {
      const int id = i * d + j, id2 = d * d - 1 - id;  // (2l-i, 2l-j)
      if (id > id2) continue;
      const float c = (((i + j) & 1) ? -inv : inv);
      const float y1 = yel(i, j);
      if (id == id2) {  // center element
        o4 = fmaf(c * y1, y1, o4);
        if constexpr (HAS_O3) o3 = fmaf(c * y1, Xl[id2], o3);
      } else {
        const float y2 = yel(2 * l - i, 2 * l - j);
        o4 = fmaf((2.0f * c) * y1, y2, o4);
        if constexpr (HAS_O3) {
          o3 = fmaf(c * y1, Xl[id2], o3);
          o3 = fmaf(c * y2, Xl[id], o3);
        }
      }
    }
  }
}

__global__ __launch_bounds__(256)
__attribute__((amdgpu_waves_per_eu(2, 2)))
void wigner_kernel(
    const float* __restrict__ x0, const float* __restrict__ x1,
    const float* __restrict__ x2, const float* __restrict__ x3,
    float* __restrict__ out, int n) {
  const int b = blockIdx.x * blockDim.x + threadIdx.x;
  if (b >= n) return;

  float X0[1], X1[9], X2[25], X3[49];
  X0[0] = x0[b];
#pragma unroll
  for (int i = 0; i < 9; ++i) X1[i] = x1[b * 9 + i];
#pragma unroll
  for (int i = 0; i < 25; ++i) X2[i] = x2[b * 25 + i];
#pragma unroll
  for (int i = 0; i < 49; ++i) X3[i] = x3[b * 49 + i];

  float o2, o3 = 0.f, o4 = 0.f;

  // full value fence: X becomes "new" values; nothing computed from old X
  // can be reused past this point; also pins schedule.
#define KEY_FENCE()                                                   \
  do {                                                                \
    opaque(X0); opaque(X1); opaque(X2); opaque(X3);                   \
    opaque1(o3); opaque1(o4);                                         \
    SCHED_FENCE();                                                    \
  } while (0)

  KEY_FENCE();

  {  // key 0_1 : (0,0) (1,1) (2,2) (3,3)  — scalar, inline
    float y = triElem<0, 0, 0, 1>(X0, X0, 0, 0)
            + triElem<1, 1, 0, 1>(X1, X1, 0, 0)
            + triElem<2, 2, 0, 1>(X2, X2, 0, 0)
            + triElem<3, 3, 0, 1>(X3, X3, 0, 0);
    o2 = y;
    o3 = fmaf(y, X0[0], o3);
    o4 = fmaf(y, y, o4);
  }
  KEY_FENCE();
  {  // key 1_1 : (0,1)x2 (1,2)x2 (2,3)x2
    auto yel = [&](int i, int j) {
      return triElem<0, 1, 1, 2>(X0, X1, i, j)
           + triElem<1, 2, 1, 2>(X1, X2, i, j)
           + triElem<2, 3, 1, 2>(X2, X3, i, j);
    };
    reduceKey<1, true>(yel, X1, o3, o4);
  }
  KEY_FENCE();
  {  // key 1_-1 : (1,1) (2,2) (3,3)
    auto yel = [&](int i, int j) {
      return triElem<1, 1, 1, 1>(X1, X1, i, j)
           + triElem<2, 2, 1, 1>(X2, X2, i, j)
           + triElem<3, 3, 1, 1>(X3, X3, i, j);
    };
    reduceKey<1, false>(yel, X1, o3, o4);
  }
  KEY_FENCE();
  {  // key 2_1 : (0,2)x2 (1,1) (1,3)x2 (2,2) (3,3)
    auto yel = [&](int i, int j) {
      return triElem<0, 2, 2, 2>(X0, X2, i, j)
           + triElem<1, 1, 2, 1>(X1, X1, i, j)
           + triElem<1, 3, 2, 2>(X1, X3, i, j)
           + triElem<2, 2, 2, 1>(X2, X2, i, j)
           + triElem<3, 3, 2, 1>(X3, X3, i, j);
    };
    reduceKey<2, true>(yel, X2, o3, o4);
  }
  KEY_FENCE();
  {  // key 2_-1 : (1,2)x2 (2,3)x2
    auto yel = [&](int i, int j) {
      return triElem<1, 2, 2, 2>(X1, X2, i, j)
           + triElem<2, 3, 2, 2>(X2, X3, i, j);
    };
    reduceKey<2, false>(yel, X2, o3, o4);
  }
  KEY_FENCE();
  {  // key 3_1 : (0,3)x2 (1,2)x2 (2,3)x2
    auto yel = [&](int i, int j) {
      return triElem<0, 3, 3, 2>(X0, X3, i, j)
           + triElem<1, 2, 3, 2>(X1, X2, i, j)
           + triElem<2, 3, 3, 2>(X2, X3, i, j);
    };
    reduceKey<3, true>(yel, X3, o3, o4);
  }
  KEY_FENCE();
  {  // key 3_-1 : (1,3)x2 (2,2) (3,3)
    auto yel = [&](int i, int j) {
      return triElem<1, 3, 3, 2>(X1, X3, i, j)
           + triElem<2, 2, 3, 1>(X2, X2, i, j)
           + triElem<3, 3, 3, 1>(X3, X3, i, j);
    };
    reduceKey<3, false>(yel, X3, o3, o4);
  }
#undef KEY_FENCE

  reinterpret_cast<float4*>(out)[b] = make_float4(X0[0], o2, o3, o4);
}

extern "C" void kernel_launch(void* const* d_in, const int* in_sizes, int n_in,
                              void* d_out, int out_size, void* d_ws, size_t ws_size,
                              hipStream_t stream) {
  const float* x0 = (const float*)d_in[0];
  const float* x1 = (const float*)d_in[1];
  const float* x2 = (const float*)d_in[2];
  const float* x3 = (const float*)d_in[3];
  float* out = (float*)d_out;
  const int n = in_sizes[0];  // B (x0 has 1 element per b)
  const int block = 256;
  const int grid = (n + block - 1) / block;
  wigner_kernel<<<grid, block, 0, stream>>>(x0, x1, x2, x3, out, n);
}